// Round 2
// baseline (432.545 us; speedup 1.0000x reference)
//
#include <hip/hip_runtime.h>

// Batched Viterbi decode: B=1024 sequences, S=512 steps, T=64 tags.
// One wave (64 lanes) per batch element; lane = "next" tag.
// Forward: per step, cand[next,prev] = fv[prev] + trans[next,prev];
//   max+argmax over prev (first-index ties, exact fp32 to match jnp).
// Backpointers: packed 4 steps/dword into LDS (32 KB/block, no HBM traffic).
// Backtrace fused: chunked LDS prefetch + readlane scalar chain.
// Output layout: path_score[B] (f32) then best_path[B,S] (tags as f32).

#define B_ 1024
#define S_ 512
#define T_ 64
#define NEGV -10000.0f

__global__ __launch_bounds__(64, 1) void viterbi_kernel(
    const float* __restrict__ feats,   // [B, S, T]
    const float* __restrict__ trans,   // [T, T]
    float* __restrict__ out)           // [B + B*S]
{
    // bp[w][tag]: word w holds backpointers for steps 4w..4w+3 (byte k = step 4w+k)
    __shared__ unsigned int bp[S_ / 4][T_];
    __shared__ __align__(16) float fvbuf[2][T_];   // double-buffered forward_var

    const int b = blockIdx.x;
    const int lane = threadIdx.x;      // = next tag

    // ---- load transitions row for next = lane into registers (64 VGPRs) ----
    float t[T_];
#pragma unroll
    for (int p = 0; p < T_; p += 4) {
        const float4 v = *reinterpret_cast<const float4*>(trans + lane * T_ + p);
        t[p] = v.x; t[p + 1] = v.y; t[p + 2] = v.z; t[p + 3] = v.w;
    }
    const float tend = trans[(T_ - 1) * T_ + lane];   // transitions[END][lane]

    // ---- init forward_var ----
    float fv = (lane == T_ - 2) ? 0.0f : NEGV;        // START = T-2
    fvbuf[0][lane] = fv;
    __syncthreads();

    const float* fb = feats + (size_t)b * S_ * T_ + lane;
    unsigned int pack = 0;

    // ---- forward scan ----
#pragma unroll 4
    for (int s = 0; s < S_; ++s) {
        const float feat = fb[(size_t)s * T_];
        const int rs = s & 1;

        // broadcast-read forward_var vector (16x ds_read_b128, same addr all lanes)
        float fvl[T_];
#pragma unroll
        for (int j = 0; j < 16; ++j) {
            const float4 v = *reinterpret_cast<const float4*>(&fvbuf[rs][4 * j]);
            fvl[4 * j] = v.x; fvl[4 * j + 1] = v.y;
            fvl[4 * j + 2] = v.z; fvl[4 * j + 3] = v.w;
        }

        // 4 independent accumulator chains over contiguous 16-blocks (ILP),
        // strict-greater update => first-index tie semantics within a block.
        float bv[4];
        int bi[4];
#pragma unroll
        for (int g = 0; g < 4; ++g) {
            float bestv = fvl[16 * g] + t[16 * g];
            int besti = 16 * g;
#pragma unroll
            for (int q = 1; q < 16; ++q) {
                const int p = 16 * g + q;
                const float c = fvl[p] + t[p];
                const bool gt = c > bestv;
                besti = gt ? p : besti;
                bestv = gt ? c : bestv;
            }
            bv[g] = bestv; bi[g] = besti;
        }
        // merge blocks in order (strict > keeps earlier block on tie => lower index)
        float BV = bv[0]; int BI = bi[0];
#pragma unroll
        for (int g = 1; g < 4; ++g) {
            const bool gt = bv[g] > BV;
            BI = gt ? bi[g] : BI;
            BV = gt ? bv[g] : BV;
        }

        fv = BV + feat;
        fvbuf[(s + 1) & 1][lane] = fv;

        pack |= ((unsigned int)BI) << (8 * (s & 3));
        if ((s & 3) == 3) {
            bp[s >> 2][lane] = pack;
            pack = 0;
        }
        __syncthreads();
    }

    // ---- terminal: max/argmax over tags (cross-lane butterfly, first-index ties) ----
    float v = fv + tend;
    int i = lane;
#pragma unroll
    for (int off = 1; off < 64; off <<= 1) {
        const float vo = __shfl_xor(v, off);
        const int io = __shfl_xor(i, off);
        const bool take = (vo > v) || ((vo == v) && (io < i));
        v = take ? vo : v;
        i = take ? io : i;
    }
    int tcur = __builtin_amdgcn_readfirstlane(i);
    if (lane == 0) out[b] = v;

    __syncthreads();

    // ---- backtrace: chunks of 64 steps, prefetch columns then readlane chain ----
    float* outp = out + B_ + (size_t)b * S_;
#pragma unroll 1
    for (int c = 7; c >= 0; --c) {
        unsigned int w[16];
#pragma unroll
        for (int j = 0; j < 16; ++j)
            w[j] = bp[16 * c + j][lane];   // lane = column (tag), conflict-free

        int emit = 0;
#pragma unroll
        for (int k = 63; k >= 0; --k) {
            // emit tag at step s = 64c + k (tcur is wave-uniform), then follow bp
            emit = (lane == k) ? tcur : emit;
            const int word = __builtin_amdgcn_readlane((int)w[k >> 2], tcur);
            tcur = (word >> (8 * (k & 3))) & 0xff;
        }
        outp[64 * c + lane] = (float)emit;   // coalesced 256B store per chunk
    }
}

extern "C" void kernel_launch(void* const* d_in, const int* in_sizes, int n_in,
                              void* d_out, int out_size, void* d_ws, size_t ws_size,
                              hipStream_t stream) {
    const float* feats = (const float*)d_in[0];   // [B*S*T] f32
    const float* trans = (const float*)d_in[1];   // [T*T] f32
    float* out = (float*)d_out;                   // [B + B*S] f32
    viterbi_kernel<<<dim3(B_), dim3(T_), 0, stream>>>(feats, trans, out);
}

// Round 3
// 432.514 us; speedup vs baseline: 1.0001x; 1.0001x over previous
//
#include <hip/hip_runtime.h>

// Batched Viterbi decode: B=1024, S=512, T=64.
// R3: 2 waves per batch element (block=128). Wave w reduces prevs [32w,32w+32);
// cross-wave combine via parity-double-buffered packed (val,idx) LDS partials,
// ONE __syncthreads per step. Private per-wave fv slice in LDS (in-order
// same-wave write->read, no barrier). feat software-prefetched 1 step ahead.
// Tie semantics identical to jnp.argmax (first index): ascending blocks,
// strict-> merges, lower-prev wave preferred on cross-wave tie.

#define B_ 1024
#define S_ 512
#define T_ 64
#define NEGV -10000.0f

__global__ __launch_bounds__(128, 2) void viterbi_kernel(
    const float* __restrict__ feats,   // [B, S, T]
    const float* __restrict__ trans,   // [T, T]
    float* __restrict__ out)           // [B + B*S]
{
    __shared__ unsigned int bp[S_ / 4][T_];                 // packed backpointers, 32 KB
    __shared__ __align__(16) float fvbuf[2][32];            // per-wave fv slice
    __shared__ unsigned long long part[2][2][T_];           // [parity][wave][lane]

    const int b    = blockIdx.x;
    const int tid  = threadIdx.x;
    const int lane = tid & 63;          // = next tag
    const int w    = tid >> 6;          // wave id: prev range [32w, 32w+32)
    const int pb   = 32 * w;

    // transitions sub-row for next=lane, prevs pb..pb+31 (32 VGPRs)
    float t[32];
#pragma unroll
    for (int p = 0; p < 32; p += 4) {
        const float4 v = *reinterpret_cast<const float4*>(trans + lane * T_ + pb + p);
        t[p] = v.x; t[p + 1] = v.y; t[p + 2] = v.z; t[p + 3] = v.w;
    }
    const float tend = trans[(T_ - 1) * T_ + lane];   // transitions[END][lane]

    // init forward_var slice (START = T-2)
    {
        const float f0 = (lane == T_ - 2) ? 0.0f : NEGV;
        const int jp = lane - pb;
        if (jp >= 0 && jp < 32) fvbuf[w][jp] = f0;
    }
    __syncthreads();

    const float* fb = feats + (size_t)b * S_ * T_ + lane;
    unsigned int pack = 0;
    float fvlast = 0.0f;
    float feat = fb[0];

#pragma unroll 4
    for (int s = 0; s < S_; ++s) {
        // prefetch next step's emission (guard last step)
        const float featn = (s + 1 < S_) ? fb[(size_t)(s + 1) * T_] : 0.0f;

        // broadcast-read own fv slice (8x ds_read_b128, same addr all lanes)
        float fvl[32];
#pragma unroll
        for (int j = 0; j < 8; ++j) {
            const float4 v = *reinterpret_cast<const float4*>(&fvbuf[w][4 * j]);
            fvl[4 * j] = v.x; fvl[4 * j + 1] = v.y;
            fvl[4 * j + 2] = v.z; fvl[4 * j + 3] = v.w;
        }

        // two independent 16-chains (ILP), strict-> => first-index ties
        float bv[2]; int bi[2];
#pragma unroll
        for (int g = 0; g < 2; ++g) {
            float bestv = fvl[16 * g] + t[16 * g];
            int besti = pb + 16 * g;
#pragma unroll
            for (int q = 1; q < 16; ++q) {
                const int p = 16 * g + q;
                const float c = fvl[p] + t[p];
                const bool gt = c > bestv;
                besti = gt ? (pb + p) : besti;
                bestv = gt ? c : bestv;
            }
            bv[g] = bestv; bi[g] = besti;
        }
        const bool g1 = bv[1] > bv[0];
        const float mv = g1 ? bv[1] : bv[0];
        const int   mi = g1 ? bi[1] : bi[0];

        // publish packed partial, exchange across waves (parity dbuf => 1 barrier)
        part[s & 1][w][lane] =
            ((unsigned long long)__float_as_uint(mv) << 32) | (unsigned int)mi;
        __syncthreads();
        const unsigned long long o = part[s & 1][1 - w][lane];
        const float ov = __uint_as_float((unsigned int)(o >> 32));
        const int   oi = (int)(unsigned int)(o & 0xffffffffu);

        // combine: lower-prev partial wins ties
        float BV; int BI;
        if (w == 0) { const bool r = ov > mv;  BV = r ? ov : mv; BI = r ? oi : mi; }
        else        { const bool r = ov >= mv; BV = r ? ov : mv; BI = r ? oi : mi; }

        const float fv = BV + feat;
        fvlast = fv;
        feat = featn;

        // write back own slice of fv (half-wave predicated)
        const int jp = lane - pb;
        if (jp >= 0 && jp < 32) fvbuf[w][jp] = fv;

        // backpointers: wave 0 only (it has combined BI on all 64 lanes)
        if (w == 0) {
            pack |= ((unsigned int)BI) << (8 * (s & 3));
            if ((s & 3) == 3) { bp[s >> 2][lane] = pack; pack = 0; }
        }
    }

    if (w != 0) return;   // terminal + backtrace on wave 0 (it wrote all of bp)

    // terminal: max/argmax over tags (butterfly, first-index ties)
    float v = fvlast + tend;
    int i = lane;
#pragma unroll
    for (int off = 1; off < 64; off <<= 1) {
        const float vo = __shfl_xor(v, off);
        const int io = __shfl_xor(i, off);
        const bool take = (vo > v) || ((vo == v) && (io < i));
        v = take ? vo : v;
        i = take ? io : i;
    }
    int tcur = __builtin_amdgcn_readfirstlane(i);
    if (lane == 0) out[b] = v;

    // backtrace: chunks of 64 steps, prefetch columns then readlane chain
    float* outp = out + B_ + (size_t)b * S_;
#pragma unroll 1
    for (int c = 7; c >= 0; --c) {
        unsigned int wd[16];
#pragma unroll
        for (int j = 0; j < 16; ++j)
            wd[j] = bp[16 * c + j][lane];   // lane = column (tag), conflict-free

        int emit = 0;
#pragma unroll
        for (int k = 63; k >= 0; --k) {
            emit = (lane == k) ? tcur : emit;          // tcur is wave-uniform
            const int word = __builtin_amdgcn_readlane((int)wd[k >> 2], tcur);
            tcur = (word >> (8 * (k & 3))) & 0xff;
        }
        outp[64 * c + lane] = (float)emit;   // coalesced 256B store per chunk
    }
}

extern "C" void kernel_launch(void* const* d_in, const int* in_sizes, int n_in,
                              void* d_out, int out_size, void* d_ws, size_t ws_size,
                              hipStream_t stream) {
    const float* feats = (const float*)d_in[0];   // [B*S*T] f32
    const float* trans = (const float*)d_in[1];   // [T*T] f32
    float* out = (float*)d_out;                   // [B + B*S] f32
    viterbi_kernel<<<dim3(B_), dim3(128), 0, stream>>>(feats, trans, out);
}

// Round 4
// 418.844 us; speedup vs baseline: 1.0327x; 1.0326x over previous
//
#include <hip/hip_runtime.h>

// Batched Viterbi decode: B=1024, S=512, T=64.
// R4: 1 wave per batch element, ZERO barriers (same-wave LDS RAW is HW-ordered;
// per-step __syncthreads forced vmcnt(0) drains that exposed global-load
// latency every step -- the R2/R3 bottleneck). feats prefetched 4 steps ahead
// (one unrolled body) so HBM latency (~900cyc) hides under ~2000cyc of compute.
// Forward: lane = next tag; 64 candidates/lane as 4 interleaved 16-deep
// strict-> chains (first-index ties, bit-exact vs jnp). Backpointers packed
// 4 steps/dword in LDS (32 KB). Fused backtrace via readlane chain.

#define B_ 1024
#define S_ 512
#define T_ 64
#define NEGV -10000.0f

__global__ __launch_bounds__(64, 1) void viterbi_kernel(
    const float* __restrict__ feats,   // [B, S, T]
    const float* __restrict__ trans,   // [T, T]
    float* __restrict__ out)           // [B + B*S]
{
    __shared__ unsigned int bp[S_ / 4][T_];        // packed backpointers, 32 KB
    __shared__ __align__(16) float fvbuf[2][T_];   // parity-double-buffered fv

    const int b = blockIdx.x;
    const int lane = threadIdx.x;      // = next tag

    // transitions row for next = lane (64 VGPRs)
    float t[T_];
#pragma unroll
    for (int p = 0; p < T_; p += 4) {
        const float4 v = *reinterpret_cast<const float4*>(trans + lane * T_ + p);
        t[p] = v.x; t[p + 1] = v.y; t[p + 2] = v.z; t[p + 3] = v.w;
    }
    const float tend = trans[(T_ - 1) * T_ + lane];   // transitions[END][lane]

    // init forward_var (START = T-2); same-wave write->read needs no barrier
    float fv = (lane == T_ - 2) ? 0.0f : NEGV;
    fvbuf[0][lane] = fv;

    const float* fb = feats + (size_t)b * S_ * T_ + lane;

    // feat prefetch ring: 4 steps (= one unrolled body) ahead
    float fc[4], fn[4];
#pragma unroll
    for (int k = 0; k < 4; ++k) fc[k] = fb[(size_t)k * T_];

#pragma unroll 1
    for (int s4 = 0; s4 < S_ / 4; ++s4) {
        // issue next body's feat loads now; consumed one body later
#pragma unroll
        for (int k = 0; k < 4; ++k) {
            int sp = 4 * s4 + 4 + k;
            sp = (sp < S_) ? sp : (S_ - 1);          // clamp (uniform scalar)
            fn[k] = fb[(size_t)sp * T_];
        }

        unsigned int pack = 0;
#pragma unroll
        for (int u = 0; u < 4; ++u) {
            const int s = 4 * s4 + u;
            const int rs = s & 1;

            // broadcast-read fv vector (16x ds_read_b128, same addr all lanes)
            float fvl[T_];
#pragma unroll
            for (int j = 0; j < 16; ++j) {
                const float4 v = *reinterpret_cast<const float4*>(&fvbuf[rs][4 * j]);
                fvl[4 * j] = v.x; fvl[4 * j + 1] = v.y;
                fvl[4 * j + 2] = v.z; fvl[4 * j + 3] = v.w;
            }

            // 4 interleaved 16-deep chains, strict-> => first-index ties
            float bv[4]; int bi[4];
#pragma unroll
            for (int g = 0; g < 4; ++g) {
                float bestv = fvl[16 * g] + t[16 * g];
                int besti = 16 * g;
#pragma unroll
                for (int q = 1; q < 16; ++q) {
                    const int p = 16 * g + q;
                    const float c = fvl[p] + t[p];
                    const bool gt = c > bestv;
                    besti = gt ? p : besti;
                    bestv = gt ? c : bestv;
                }
                bv[g] = bestv; bi[g] = besti;
            }
            float BV = bv[0]; int BI = bi[0];
#pragma unroll
            for (int g = 1; g < 4; ++g) {
                const bool gt = bv[g] > BV;   // strict > keeps lower block on tie
                BI = gt ? bi[g] : BI;
                BV = gt ? bv[g] : BV;
            }

            fv = BV + fc[u];
            fvbuf[rs ^ 1][lane] = fv;
            pack |= ((unsigned int)BI) << (8 * u);
        }
        bp[s4][lane] = pack;

#pragma unroll
        for (int k = 0; k < 4; ++k) fc[k] = fn[k];
    }

    // terminal: max/argmax over tags (butterfly, first-index ties)
    float v = fv + tend;
    int i = lane;
#pragma unroll
    for (int off = 1; off < 64; off <<= 1) {
        const float vo = __shfl_xor(v, off);
        const int io = __shfl_xor(i, off);
        const bool take = (vo > v) || ((vo == v) && (io < i));
        v = take ? vo : v;
        i = take ? io : i;
    }
    int tcur = __builtin_amdgcn_readfirstlane(i);
    if (lane == 0) out[b] = v;

    // backtrace: chunks of 64 steps, prefetch columns then readlane chain
    float* outp = out + B_ + (size_t)b * S_;
#pragma unroll 1
    for (int c = 7; c >= 0; --c) {
        unsigned int wd[16];
#pragma unroll
        for (int j = 0; j < 16; ++j)
            wd[j] = bp[16 * c + j][lane];   // lane = column (tag), conflict-free

        int emit = 0;
#pragma unroll
        for (int k = 63; k >= 0; --k) {
            emit = (lane == k) ? tcur : emit;          // tcur is wave-uniform
            const int word = __builtin_amdgcn_readlane((int)wd[k >> 2], tcur);
            tcur = (word >> (8 * (k & 3))) & 0xff;
        }
        outp[64 * c + lane] = (float)emit;   // coalesced 256B store per chunk
    }
}

extern "C" void kernel_launch(void* const* d_in, const int* in_sizes, int n_in,
                              void* d_out, int out_size, void* d_ws, size_t ws_size,
                              hipStream_t stream) {
    const float* feats = (const float*)d_in[0];   // [B*S*T] f32
    const float* trans = (const float*)d_in[1];   // [T*T] f32
    float* out = (float*)d_out;                   // [B + B*S] f32
    viterbi_kernel<<<dim3(B_), dim3(T_), 0, stream>>>(feats, trans, out);
}